// Round 1
// baseline (1897.199 us; speedup 1.0000x reference)
//
#include <hip/hip_runtime.h>

// RGCN 2-layer forward, f32.
// L1: agg1[n,r,:] = sum_{e: dst=n,et=r} x[src_e]; h = relu([agg1*inv_cnt | x] @ [W_rel1;W_root1] + b1)
// L2: per-edge t = h[src] @ W_rel2[et] (2 outs), atomic into agg2[n,r,0:2]; out = sum_r agg2*inv_cnt + h@W_root2 + b2

#define NR 8
#define DH 128

__global__ __launch_bounds__(256) void k_count(const int* __restrict__ dst, const int* __restrict__ et,
                                               float* __restrict__ cnt, int E) {
  int e = blockIdx.x * 256 + threadIdx.x;
  if (e < E) atomicAdd(&cnt[dst[e] * NR + et[e]], 1.0f);
}

__global__ __launch_bounds__(256) void k_scatter1(const int* __restrict__ src, const int* __restrict__ dst,
                                                  const int* __restrict__ et, const float* __restrict__ x,
                                                  float* __restrict__ agg1, int E) {
  long long gid = (long long)blockIdx.x * 256 + threadIdx.x;
  int e = (int)(gid >> 5);
  int lane = (int)(gid & 31);
  if (e >= E) return;
  int s = src[e];
  int seg = dst[e] * NR + et[e];
  float4 v = ((const float4*)(x + (size_t)s * DH))[lane];
  float* d = agg1 + (size_t)seg * DH + lane * 4;
  atomicAdd(d + 0, v.x);
  atomicAdd(d + 1, v.y);
  atomicAdd(d + 2, v.z);
  atomicAdd(d + 3, v.w);
}

// C[N,128] = A[N,1152] x W[1152,128]; A = [agg1*inv | x], W = [W_rel1 ; W_root1]. BM=64, BN=128, BK=32.
__global__ __launch_bounds__(256) void k_gemm1(const float* __restrict__ agg1, const float* __restrict__ x,
                                               const float* __restrict__ cnt, const float* __restrict__ W1,
                                               const float* __restrict__ Wr1, const float* __restrict__ b1,
                                               float* __restrict__ h, int N) {
  __shared__ float As[64 * 33];
  __shared__ float Bs[32 * 132];
  __shared__ float invc[64 * 8];
  int tid = threadIdx.x;
  int n0 = blockIdx.x * 64;

  #pragma unroll
  for (int i = 0; i < 2; i++) {
    int idx = tid + i * 256;           // 512 values
    int row = idx >> 3, r = idx & 7;
    int n = n0 + row;
    float c = (n < N) ? cnt[n * NR + r] : 1.f;
    invc[idx] = 1.f / fmaxf(c, 1.f);
  }
  __syncthreads();

  float acc[4][8];
  #pragma unroll
  for (int i = 0; i < 4; i++)
    #pragma unroll
    for (int j = 0; j < 8; j++) acc[i][j] = 0.f;

  int row0 = (tid >> 4) * 4;
  int col0 = (tid & 15) * 8;

  for (int kc = 0; kc < 36; kc++) {
    // stage A: 64x32
    #pragma unroll
    for (int i = 0; i < 2; i++) {
      int flat = i * 1024 + tid * 4;
      int row = flat >> 5, kk = flat & 31;
      int n = n0 + row;
      int k = kc * 32 + kk;
      float4 v = make_float4(0.f, 0.f, 0.f, 0.f);
      if (n < N) {
        if (k < 1024) {
          v = *(const float4*)(agg1 + (size_t)n * 1024 + k);
          float sc = invc[row * 8 + (k >> 7)];
          v.x *= sc; v.y *= sc; v.z *= sc; v.w *= sc;
        } else {
          v = *(const float4*)(x + (size_t)n * DH + (k - 1024));
        }
      }
      float* a = As + row * 33 + kk;
      a[0] = v.x; a[1] = v.y; a[2] = v.z; a[3] = v.w;
    }
    // stage B: 32x128
    #pragma unroll
    for (int i = 0; i < 4; i++) {
      int flat = i * 1024 + tid * 4;
      int kk = flat >> 7, col = flat & 127;
      int k = kc * 32 + kk;
      const float* sp = (k < 1024) ? (W1 + (size_t)k * DH + col)
                                   : (Wr1 + (size_t)(k - 1024) * DH + col);
      *(float4*)(Bs + kk * 132 + col) = *(const float4*)sp;
    }
    __syncthreads();
    #pragma unroll
    for (int kk = 0; kk < 32; kk++) {
      float a0 = As[(row0 + 0) * 33 + kk];
      float a1 = As[(row0 + 1) * 33 + kk];
      float a2 = As[(row0 + 2) * 33 + kk];
      float a3 = As[(row0 + 3) * 33 + kk];
      float4 bl = *(const float4*)(Bs + kk * 132 + col0);
      float4 bh = *(const float4*)(Bs + kk * 132 + col0 + 4);
      float av[4] = {a0, a1, a2, a3};
      float bv[8] = {bl.x, bl.y, bl.z, bl.w, bh.x, bh.y, bh.z, bh.w};
      #pragma unroll
      for (int i = 0; i < 4; i++)
        #pragma unroll
        for (int j = 0; j < 8; j++) acc[i][j] += av[i] * bv[j];
    }
    __syncthreads();
  }

  #pragma unroll
  for (int i = 0; i < 4; i++) {
    int n = n0 + row0 + i;
    if (n < N) {
      float4 o0, o1;
      o0.x = fmaxf(acc[i][0] + b1[col0 + 0], 0.f);
      o0.y = fmaxf(acc[i][1] + b1[col0 + 1], 0.f);
      o0.z = fmaxf(acc[i][2] + b1[col0 + 2], 0.f);
      o0.w = fmaxf(acc[i][3] + b1[col0 + 3], 0.f);
      o1.x = fmaxf(acc[i][4] + b1[col0 + 4], 0.f);
      o1.y = fmaxf(acc[i][5] + b1[col0 + 5], 0.f);
      o1.z = fmaxf(acc[i][6] + b1[col0 + 6], 0.f);
      o1.w = fmaxf(acc[i][7] + b1[col0 + 7], 0.f);
      *(float4*)(h + (size_t)n * DH + col0) = o0;
      *(float4*)(h + (size_t)n * DH + col0 + 4) = o1;
    }
  }
}

__global__ __launch_bounds__(256) void k_edge2(const int* __restrict__ src, const int* __restrict__ dst,
                                               const int* __restrict__ et, const float* __restrict__ h,
                                               const float* __restrict__ W2, float* __restrict__ agg2, int E) {
  long long gid = (long long)blockIdx.x * 256 + threadIdx.x;
  int e = (int)(gid >> 5);
  int lane = (int)(gid & 31);
  if (e >= E) return;
  int s = src[e];
  int t = et[e];
  int seg = dst[e] * NR + t;
  float4 v = ((const float4*)(h + (size_t)s * DH))[lane];
  const float4* wr = (const float4*)(W2 + (size_t)t * 256 + lane * 8);
  float4 w0 = wr[0];  // rows d0,d1 (cols 0,1 interleaved)
  float4 w1 = wr[1];  // rows d2,d3
  float t0 = v.x * w0.x + v.y * w0.z + v.z * w1.x + v.w * w1.z;
  float t1 = v.x * w0.y + v.y * w0.w + v.z * w1.y + v.w * w1.w;
  #pragma unroll
  for (int m = 16; m >= 1; m >>= 1) {
    t0 += __shfl_xor(t0, m, 32);
    t1 += __shfl_xor(t1, m, 32);
  }
  if (lane == 0) {
    atomicAdd(&agg2[(size_t)seg * 2 + 0], t0);
    atomicAdd(&agg2[(size_t)seg * 2 + 1], t1);
  }
}

__global__ __launch_bounds__(256) void k_out(const float* __restrict__ h, const float* __restrict__ cnt,
                                             const float* __restrict__ agg2, const float* __restrict__ Wr2,
                                             const float* __restrict__ b2, float* __restrict__ out, int N) {
  long long gid = (long long)blockIdx.x * 256 + threadIdx.x;
  int n = (int)(gid >> 5);
  int lane = (int)(gid & 31);
  if (n >= N) return;
  float4 v = ((const float4*)(h + (size_t)n * DH))[lane];
  const float4* wr = (const float4*)(Wr2 + lane * 8);
  float4 w0 = wr[0];
  float4 w1 = wr[1];
  float t0 = v.x * w0.x + v.y * w0.z + v.z * w1.x + v.w * w1.z;
  float t1 = v.x * w0.y + v.y * w0.w + v.z * w1.y + v.w * w1.w;
  #pragma unroll
  for (int m = 16; m >= 1; m >>= 1) {
    t0 += __shfl_xor(t0, m, 32);
    t1 += __shfl_xor(t1, m, 32);
  }
  if (lane == 0) {
    float o0 = t0 + b2[0];
    float o1 = t1 + b2[1];
    #pragma unroll
    for (int r = 0; r < NR; r++) {
      float c = cnt[n * NR + r];
      float inv = 1.f / fmaxf(c, 1.f);
      o0 += agg2[((size_t)n * NR + r) * 2 + 0] * inv;
      o1 += agg2[((size_t)n * NR + r) * 2 + 1] * inv;
    }
    out[(size_t)n * 2 + 0] = o0;
    out[(size_t)n * 2 + 1] = o1;
  }
}

extern "C" void kernel_launch(void* const* d_in, const int* in_sizes, int n_in,
                              void* d_out, int out_size, void* d_ws, size_t ws_size,
                              hipStream_t stream) {
  const float* x   = (const float*)d_in[0];
  const int*   ei  = (const int*)d_in[1];
  const int*   et  = (const int*)d_in[2];
  const float* W1  = (const float*)d_in[3];
  const float* Wr1 = (const float*)d_in[4];
  const float* b1  = (const float*)d_in[5];
  const float* W2  = (const float*)d_in[6];
  const float* Wr2 = (const float*)d_in[7];
  const float* b2  = (const float*)d_in[8];
  float* out = (float*)d_out;

  int E = in_sizes[1] / 2;
  int N = in_sizes[0] / DH;
  const int* src = ei;
  const int* dst = ei + E;

  float* ws   = (float*)d_ws;
  float* cnt  = ws;                               // N*R
  float* agg1 = cnt + (size_t)N * NR;             // N*R*128
  float* h    = agg1 + (size_t)N * NR * DH;       // N*128
  float* agg2 = h + (size_t)N * DH;               // N*R*2

  // zero cnt+agg1 (contiguous) and agg2; h is fully overwritten
  hipMemsetAsync(cnt, 0, sizeof(float) * ((size_t)N * NR + (size_t)N * NR * DH), stream);
  hipMemsetAsync(agg2, 0, sizeof(float) * (size_t)N * NR * 2, stream);

  k_count<<<(E + 255) / 256, 256, 0, stream>>>(dst, et, cnt, E);

  long long th1 = (long long)E * 32;
  k_scatter1<<<(int)((th1 + 255) / 256), 256, 0, stream>>>(src, dst, et, x, agg1, E);

  k_gemm1<<<(N + 63) / 64, 256, 0, stream>>>(agg1, x, cnt, W1, Wr1, b1, h, N);

  k_edge2<<<(int)((th1 + 255) / 256), 256, 0, stream>>>(src, dst, et, h, W2, agg2, E);

  long long th2 = (long long)N * 32;
  k_out<<<(int)((th2 + 255) / 256), 256, 0, stream>>>(h, cnt, agg2, Wr2, b2, out, N);
}

// Round 2
// 755.195 us; speedup vs baseline: 2.5122x; 2.5122x over previous
//
#include <hip/hip_runtime.h>

// RGCN 2-layer forward, f32 — CSR-gather version (no float atomics).
// Sort edges by seg = dst*8+et (counting sort). Then:
// L1: agg1[seg,:] = mean_{e in seg} x[src_e]  (one wave per segment, gather)
//     h = relu([agg1 | x] @ [W_rel1;W_root1] + b1)   (tiled f32 GEMM, K=1152)
// L2: agg2[seg,0:2] = (mean_{e in seg} h[src_e]) @ W_rel2[r]  (wave per segment)
//     out = sum_r agg2[n,r,:] + h @ W_root2 + b2

#define NR 8
#define DH 128

// ---------- counting sort ----------
__global__ __launch_bounds__(256) void k_hist(const int* __restrict__ dst, const int* __restrict__ et,
                                              int* __restrict__ hist, int E) {
  int e = blockIdx.x * 256 + threadIdx.x;
  if (e < E) atomicAdd(&hist[dst[e] * NR + et[e]], 1);
}

// per-block exclusive scan over 1024 elements, block totals out
__global__ __launch_bounds__(256) void k_scan_local(const int* __restrict__ hist, int* __restrict__ offs,
                                                    int* __restrict__ blksum, int S) {
  __shared__ int tsum[256];
  int tid = threadIdx.x;
  int base = blockIdx.x * 1024 + tid * 4;
  int v[4], tot = 0;
  #pragma unroll
  for (int i = 0; i < 4; i++) { v[i] = (base + i < S) ? hist[base + i] : 0; tot += v[i]; }
  tsum[tid] = tot;
  __syncthreads();
  for (int off = 1; off < 256; off <<= 1) {
    int val = tsum[tid];
    int add = (tid >= off) ? tsum[tid - off] : 0;
    __syncthreads();
    tsum[tid] = val + add;
    __syncthreads();
  }
  int run = tsum[tid] - tot;  // exclusive within block
  #pragma unroll
  for (int i = 0; i < 4; i++) {
    if (base + i < S) offs[base + i] = run;
    run += v[i];
  }
  if (tid == 255) blksum[blockIdx.x] = tsum[255];
}

__global__ __launch_bounds__(512) void k_scan_blk(const int* __restrict__ blksum, int* __restrict__ blkoff, int NB) {
  __shared__ int s[512];
  int tid = threadIdx.x;
  int v = (tid < NB) ? blksum[tid] : 0;
  s[tid] = v;
  __syncthreads();
  for (int off = 1; off < 512; off <<= 1) {
    int val = s[tid];
    int add = (tid >= off) ? s[tid - off] : 0;
    __syncthreads();
    s[tid] = val + add;
    __syncthreads();
  }
  if (tid < NB) blkoff[tid] = s[tid] - v;
}

__global__ __launch_bounds__(256) void k_scan_add(int* __restrict__ offs, const int* __restrict__ blkoff, int S) {
  int tid = threadIdx.x;
  int base = blockIdx.x * 1024 + tid * 4;
  int add = blkoff[blockIdx.x];
  #pragma unroll
  for (int i = 0; i < 4; i++)
    if (base + i < S) offs[base + i] += add;
}

// scatter edge src into sorted order; offs[seg] becomes segment END afterwards
__global__ __launch_bounds__(256) void k_scatter_idx(const int* __restrict__ src, const int* __restrict__ dst,
                                                     const int* __restrict__ et, int* __restrict__ offs,
                                                     int* __restrict__ sorted_src, int E) {
  int e = blockIdx.x * 256 + threadIdx.x;
  if (e >= E) return;
  int seg = dst[e] * NR + et[e];
  int pos = atomicAdd(&offs[seg], 1);
  sorted_src[pos] = src[e];
}

// ---------- layer 1 aggregate: one wave64 per segment ----------
__global__ __launch_bounds__(256) void k_agg1(const int* __restrict__ offs, const int* __restrict__ hist,
                                              const int* __restrict__ sorted_src, const float* __restrict__ x,
                                              float* __restrict__ agg1, int S) {
  int tid = threadIdx.x;
  int seg = blockIdx.x * 4 + (tid >> 6);
  int lane = tid & 63;
  if (seg >= S) return;
  int end = offs[seg];
  int cnt = hist[seg];
  int st = end - cnt;
  float2 a = make_float2(0.f, 0.f);
  for (int i = st; i < end; i++) {
    int s = sorted_src[i];
    float2 v = *(const float2*)(x + (size_t)s * DH + lane * 2);
    a.x += v.x;
    a.y += v.y;
  }
  float inv = 1.f / fmaxf((float)cnt, 1.f);
  a.x *= inv;
  a.y *= inv;
  *(float2*)(agg1 + (size_t)seg * DH + lane * 2) = a;
}

// ---------- layer 1 GEMM: C[N,128] = [agg1 | x] @ [W_rel1;W_root1], BM=64 BN=128 BK=32 ----------
__global__ __launch_bounds__(256) void k_gemm1(const float* __restrict__ agg1, const float* __restrict__ x,
                                               const float* __restrict__ W1, const float* __restrict__ Wr1,
                                               const float* __restrict__ b1, float* __restrict__ h, int N) {
  __shared__ float As[64 * 33];
  __shared__ float Bs[32 * 132];
  int tid = threadIdx.x;
  int n0 = blockIdx.x * 64;

  float acc[4][8];
  #pragma unroll
  for (int i = 0; i < 4; i++)
    #pragma unroll
    for (int j = 0; j < 8; j++) acc[i][j] = 0.f;

  int row0 = (tid >> 4) * 4;
  int col0 = (tid & 15) * 8;

  for (int kc = 0; kc < 36; kc++) {
    #pragma unroll
    for (int i = 0; i < 2; i++) {
      int flat = i * 1024 + tid * 4;
      int row = flat >> 5, kk = flat & 31;
      int n = n0 + row;
      int k = kc * 32 + kk;
      float4 v = make_float4(0.f, 0.f, 0.f, 0.f);
      if (n < N) {
        if (k < 1024) v = *(const float4*)(agg1 + (size_t)n * 1024 + k);
        else          v = *(const float4*)(x + (size_t)n * DH + (k - 1024));
      }
      float* a = As + row * 33 + kk;
      a[0] = v.x; a[1] = v.y; a[2] = v.z; a[3] = v.w;
    }
    #pragma unroll
    for (int i = 0; i < 4; i++) {
      int flat = i * 1024 + tid * 4;
      int kk = flat >> 7, col = flat & 127;
      int k = kc * 32 + kk;
      const float* sp = (k < 1024) ? (W1 + (size_t)k * DH + col)
                                   : (Wr1 + (size_t)(k - 1024) * DH + col);
      *(float4*)(Bs + kk * 132 + col) = *(const float4*)sp;
    }
    __syncthreads();
    #pragma unroll
    for (int kk = 0; kk < 32; kk++) {
      float av[4];
      #pragma unroll
      for (int i = 0; i < 4; i++) av[i] = As[(row0 + i) * 33 + kk];
      float4 bl = *(const float4*)(Bs + kk * 132 + col0);
      float4 bh = *(const float4*)(Bs + kk * 132 + col0 + 4);
      float bv[8] = {bl.x, bl.y, bl.z, bl.w, bh.x, bh.y, bh.z, bh.w};
      #pragma unroll
      for (int i = 0; i < 4; i++)
        #pragma unroll
        for (int j = 0; j < 8; j++) acc[i][j] += av[i] * bv[j];
    }
    __syncthreads();
  }

  #pragma unroll
  for (int i = 0; i < 4; i++) {
    int n = n0 + row0 + i;
    if (n < N) {
      float4 o0, o1;
      o0.x = fmaxf(acc[i][0] + b1[col0 + 0], 0.f);
      o0.y = fmaxf(acc[i][1] + b1[col0 + 1], 0.f);
      o0.z = fmaxf(acc[i][2] + b1[col0 + 2], 0.f);
      o0.w = fmaxf(acc[i][3] + b1[col0 + 3], 0.f);
      o1.x = fmaxf(acc[i][4] + b1[col0 + 4], 0.f);
      o1.y = fmaxf(acc[i][5] + b1[col0 + 5], 0.f);
      o1.z = fmaxf(acc[i][6] + b1[col0 + 6], 0.f);
      o1.w = fmaxf(acc[i][7] + b1[col0 + 7], 0.f);
      *(float4*)(h + (size_t)n * DH + col0) = o0;
      *(float4*)(h + (size_t)n * DH + col0 + 4) = o1;
    }
  }
}

// ---------- layer 2 per-segment: agg2[seg,:] = mean_h(seg) @ W_rel2[r] ----------
__global__ __launch_bounds__(256) void k_l2seg(const int* __restrict__ offs, const int* __restrict__ hist,
                                               const int* __restrict__ sorted_src, const float* __restrict__ h,
                                               const float* __restrict__ W2, float* __restrict__ agg2, int S) {
  int tid = threadIdx.x;
  int seg = blockIdx.x * 4 + (tid >> 6);
  int lane = tid & 63;
  if (seg >= S) return;
  int end = offs[seg];
  int cnt = hist[seg];
  int st = end - cnt;
  float2 a = make_float2(0.f, 0.f);
  for (int i = st; i < end; i++) {
    int s = sorted_src[i];
    float2 v = *(const float2*)(h + (size_t)s * DH + lane * 2);
    a.x += v.x;
    a.y += v.y;
  }
  int r = seg & (NR - 1);
  float4 w = *(const float4*)(W2 + (size_t)r * 256 + lane * 4);  // {W(d0,0),W(d0,1),W(d1,0),W(d1,1)}
  float t0 = a.x * w.x + a.y * w.z;
  float t1 = a.x * w.y + a.y * w.w;
  #pragma unroll
  for (int m = 32; m >= 1; m >>= 1) {
    t0 += __shfl_xor(t0, m);
    t1 += __shfl_xor(t1, m);
  }
  if (lane == 0) {
    float inv = 1.f / fmaxf((float)cnt, 1.f);
    agg2[(size_t)seg * 2 + 0] = t0 * inv;
    agg2[(size_t)seg * 2 + 1] = t1 * inv;
  }
}

// ---------- output: out[n] = sum_r agg2[n,r,:] + h[n] @ W_root2 + b2 ----------
__global__ __launch_bounds__(256) void k_out(const float* __restrict__ h, const float* __restrict__ agg2,
                                             const float* __restrict__ Wr2, const float* __restrict__ b2,
                                             float* __restrict__ out, int N) {
  long long gid = (long long)blockIdx.x * 256 + threadIdx.x;
  int n = (int)(gid >> 5);
  int lane = (int)(gid & 31);
  if (n >= N) return;
  float4 v = ((const float4*)(h + (size_t)n * DH))[lane];
  const float4* wr = (const float4*)(Wr2 + lane * 8);
  float4 w0 = wr[0];
  float4 w1 = wr[1];
  float t0 = v.x * w0.x + v.y * w0.z + v.z * w1.x + v.w * w1.z;
  float t1 = v.x * w0.y + v.y * w0.w + v.z * w1.y + v.w * w1.w;
  #pragma unroll
  for (int m = 16; m >= 1; m >>= 1) {
    t0 += __shfl_xor(t0, m, 32);
    t1 += __shfl_xor(t1, m, 32);
  }
  if (lane == 0) {
    float o0 = t0 + b2[0];
    float o1 = t1 + b2[1];
    #pragma unroll
    for (int r = 0; r < NR; r++) {
      o0 += agg2[((size_t)n * NR + r) * 2 + 0];
      o1 += agg2[((size_t)n * NR + r) * 2 + 1];
    }
    out[(size_t)n * 2 + 0] = o0;
    out[(size_t)n * 2 + 1] = o1;
  }
}

extern "C" void kernel_launch(void* const* d_in, const int* in_sizes, int n_in,
                              void* d_out, int out_size, void* d_ws, size_t ws_size,
                              hipStream_t stream) {
  const float* x   = (const float*)d_in[0];
  const int*   ei  = (const int*)d_in[1];
  const int*   et  = (const int*)d_in[2];
  const float* W1  = (const float*)d_in[3];
  const float* Wr1 = (const float*)d_in[4];
  const float* b1  = (const float*)d_in[5];
  const float* W2  = (const float*)d_in[6];
  const float* Wr2 = (const float*)d_in[7];
  const float* b2  = (const float*)d_in[8];
  float* out = (float*)d_out;

  int E = in_sizes[1] / 2;
  int N = in_sizes[0] / DH;
  int S = N * NR;
  const int* src = ei;
  const int* dst = ei + E;

  // workspace layout (ints first, 16B-aligned blocks)
  int* hist       = (int*)d_ws;                  // S
  int* offs       = hist + S;                    // S
  int* blksum     = offs + S;                    // 1024
  int* blkoff     = blksum + 1024;               // 1024
  int* sorted_src = blkoff + 1024;               // E
  size_t int_elems = (size_t)S * 2 + 2048 + E;
  int_elems = (int_elems + 3) & ~(size_t)3;      // 16B align
  float* agg1 = (float*)(hist + int_elems);      // S*128
  float* h    = agg1 + (size_t)S * DH;           // N*128
  float* agg2 = h + (size_t)N * DH;              // S*2

  hipMemsetAsync(hist, 0, sizeof(int) * (size_t)S, stream);

  k_hist<<<(E + 255) / 256, 256, 0, stream>>>(dst, et, hist, E);

  int NB = (S + 1023) / 1024;  // 391 for N=50000 (must be <= 512)
  k_scan_local<<<NB, 256, 0, stream>>>(hist, offs, blksum, S);
  k_scan_blk<<<1, 512, 0, stream>>>(blksum, blkoff, NB);
  k_scan_add<<<NB, 256, 0, stream>>>(offs, blkoff, S);

  k_scatter_idx<<<(E + 255) / 256, 256, 0, stream>>>(src, dst, et, offs, sorted_src, E);

  k_agg1<<<(S + 3) / 4, 256, 0, stream>>>(offs, hist, sorted_src, x, agg1, S);

  k_gemm1<<<(N + 63) / 64, 256, 0, stream>>>(agg1, x, W1, Wr1, b1, h, N);

  k_l2seg<<<(S + 3) / 4, 256, 0, stream>>>(offs, hist, sorted_src, h, W2, agg2, S);

  long long th2 = (long long)N * 32;
  k_out<<<(int)((th2 + 255) / 256), 256, 0, stream>>>(h, agg2, Wr2, b2, out, N);
}

// Round 3
// 705.831 us; speedup vs baseline: 2.6879x; 1.0699x over previous
//
#include <hip/hip_runtime.h>

// RGCN 2-layer forward, f32 — CSR-gather version (no float atomics).
// Sort edges by seg = dst*8+et (counting sort). Then:
// L1: agg1[seg,:] = mean_{e in seg} x[src_e]  (one wave per segment, gather)
//     h = relu([agg1 | x] @ [W_rel1;W_root1] + b1)   (tiled f32 GEMM, K=1152)
// L2: agg2[seg,0:2] = (mean_{e in seg} h[src_e]) @ W_rel2[r]  (wave per segment)
//     out = sum_r agg2[n,r,:] + h @ W_root2 + b2

#define NR 8
#define DH 128

// ---------- counting sort ----------
__global__ __launch_bounds__(256) void k_hist(const int* __restrict__ dst, const int* __restrict__ et,
                                              int* __restrict__ hist, int E) {
  int e = blockIdx.x * 256 + threadIdx.x;
  if (e < E) atomicAdd(&hist[dst[e] * NR + et[e]], 1);
}

// per-block exclusive scan over 1024 elements, block totals out
__global__ __launch_bounds__(256) void k_scan_local(const int* __restrict__ hist, int* __restrict__ offs,
                                                    int* __restrict__ blksum, int S) {
  __shared__ int tsum[256];
  int tid = threadIdx.x;
  int base = blockIdx.x * 1024 + tid * 4;
  int v[4], tot = 0;
  #pragma unroll
  for (int i = 0; i < 4; i++) { v[i] = (base + i < S) ? hist[base + i] : 0; tot += v[i]; }
  tsum[tid] = tot;
  __syncthreads();
  for (int off = 1; off < 256; off <<= 1) {
    int val = tsum[tid];
    int add = (tid >= off) ? tsum[tid - off] : 0;
    __syncthreads();
    tsum[tid] = val + add;
    __syncthreads();
  }
  int run = tsum[tid] - tot;  // exclusive within block
  #pragma unroll
  for (int i = 0; i < 4; i++) {
    if (base + i < S) offs[base + i] = run;
    run += v[i];
  }
  if (tid == 255) blksum[blockIdx.x] = tsum[255];
}

__global__ __launch_bounds__(512) void k_scan_blk(const int* __restrict__ blksum, int* __restrict__ blkoff, int NB) {
  __shared__ int s[512];
  int tid = threadIdx.x;
  int v = (tid < NB) ? blksum[tid] : 0;
  s[tid] = v;
  __syncthreads();
  for (int off = 1; off < 512; off <<= 1) {
    int val = s[tid];
    int add = (tid >= off) ? s[tid - off] : 0;
    __syncthreads();
    s[tid] = val + add;
    __syncthreads();
  }
  if (tid < NB) blkoff[tid] = s[tid] - v;
}

__global__ __launch_bounds__(256) void k_scan_add(int* __restrict__ offs, const int* __restrict__ blkoff, int S) {
  int tid = threadIdx.x;
  int base = blockIdx.x * 1024 + tid * 4;
  int add = blkoff[blockIdx.x];
  #pragma unroll
  for (int i = 0; i < 4; i++)
    if (base + i < S) offs[base + i] += add;
}

// scatter edge src into sorted order; offs[seg] becomes segment END afterwards
__global__ __launch_bounds__(256) void k_scatter_idx(const int* __restrict__ src, const int* __restrict__ dst,
                                                     const int* __restrict__ et, int* __restrict__ offs,
                                                     int* __restrict__ sorted_src, int E) {
  int e = blockIdx.x * 256 + threadIdx.x;
  if (e >= E) return;
  int seg = dst[e] * NR + et[e];
  int pos = atomicAdd(&offs[seg], 1);
  sorted_src[pos] = src[e];
}

// ---------- layer 1 aggregate: one wave64 per segment ----------
__global__ __launch_bounds__(256) void k_agg1(const int* __restrict__ offs, const int* __restrict__ hist,
                                              const int* __restrict__ sorted_src, const float* __restrict__ x,
                                              float* __restrict__ agg1, int S) {
  int tid = threadIdx.x;
  int seg = blockIdx.x * 4 + (tid >> 6);
  int lane = tid & 63;
  if (seg >= S) return;
  int end = offs[seg];
  int cnt = hist[seg];
  int st = end - cnt;
  float2 a = make_float2(0.f, 0.f);
  for (int i = st; i < end; i++) {
    int s = sorted_src[i];
    float2 v = *(const float2*)(x + (size_t)s * DH + lane * 2);
    a.x += v.x;
    a.y += v.y;
  }
  float inv = 1.f / fmaxf((float)cnt, 1.f);
  a.x *= inv;
  a.y *= inv;
  *(float2*)(agg1 + (size_t)seg * DH + lane * 2) = a;
}

// ---------- layer 1 GEMM: C[N,128] = [agg1 | x] @ [W_rel1;W_root1], BM=64 BN=128 BK=32 ----------
// Thread tile: 4 rows x (4+4 cols split at +64) — Bs reads are stride-16B contiguous
// (2-way bank aliasing only, free). Register prefetch of kc+1 overlaps global latency.
__global__ __launch_bounds__(256) void k_gemm1(const float* __restrict__ agg1, const float* __restrict__ x,
                                               const float* __restrict__ W1, const float* __restrict__ Wr1,
                                               const float* __restrict__ b1, float* __restrict__ h, int N) {
  __shared__ float As[64 * 33];
  __shared__ float Bs[32 * 132];
  int tid = threadIdx.x;
  int n0 = blockIdx.x * 64;

  float acc[4][8];
  #pragma unroll
  for (int i = 0; i < 4; i++)
    #pragma unroll
    for (int j = 0; j < 8; j++) acc[i][j] = 0.f;

  int row0 = (tid >> 4) * 4;
  int c    = (tid & 15) * 4;

  // staging coords
  int akk  = (tid & 7) * 4;   // A: col within 32-wide k-tile
  int arow = tid >> 3;        // A: row (0..31), +32 for i=1
  int bcol = (tid & 31) * 4;  // B: col within 128
  int bkk  = tid >> 5;        // B: k-row (0..7), +8*i

  float4 ra[2], rb[4];

  #define LOADA(kc)                                                                 \
    {                                                                               \
      const float* base_; size_t str_; int kb_;                                     \
      if ((kc) < 32) { base_ = agg1; str_ = 1024; kb_ = (kc) * 32; }                \
      else           { base_ = x;    str_ = 128;  kb_ = ((kc) - 32) * 32; }         \
      _Pragma("unroll")                                                             \
      for (int i_ = 0; i_ < 2; i_++) {                                              \
        int n_ = n0 + i_ * 32 + arow;                                               \
        ra[i_] = (n_ < N) ? *(const float4*)(base_ + (size_t)n_ * str_ + kb_ + akk) \
                          : make_float4(0.f, 0.f, 0.f, 0.f);                        \
      }                                                                             \
    }
  #define LOADB(kc)                                                                 \
    {                                                                               \
      const float* base_; int kb_;                                                  \
      if ((kc) < 32) { base_ = W1;  kb_ = (kc) * 32; }                              \
      else           { base_ = Wr1; kb_ = ((kc) - 32) * 32; }                       \
      _Pragma("unroll")                                                             \
      for (int i_ = 0; i_ < 4; i_++)                                                \
        rb[i_] = *(const float4*)(base_ + (size_t)(kb_ + i_ * 8 + bkk) * 128 + bcol); \
    }

  LOADA(0);
  LOADB(0);

  for (int kc = 0; kc < 36; kc++) {
    // regs -> LDS
    #pragma unroll
    for (int i = 0; i < 2; i++) {
      float* a = As + (i * 32 + arow) * 33 + akk;
      a[0] = ra[i].x; a[1] = ra[i].y; a[2] = ra[i].z; a[3] = ra[i].w;
    }
    #pragma unroll
    for (int i = 0; i < 4; i++)
      *(float4*)(Bs + (i * 8 + bkk) * 132 + bcol) = rb[i];
    __syncthreads();

    if (kc + 1 < 36) {
      LOADA(kc + 1);
      LOADB(kc + 1);
    }

    #pragma unroll
    for (int kk = 0; kk < 32; kk++) {
      float av[4];
      #pragma unroll
      for (int i = 0; i < 4; i++) av[i] = As[(row0 + i) * 33 + kk];
      float4 b0 = *(const float4*)(Bs + kk * 132 + c);
      float4 b1v = *(const float4*)(Bs + kk * 132 + c + 64);
      #pragma unroll
      for (int i = 0; i < 4; i++) {
        acc[i][0] += av[i] * b0.x;
        acc[i][1] += av[i] * b0.y;
        acc[i][2] += av[i] * b0.z;
        acc[i][3] += av[i] * b0.w;
        acc[i][4] += av[i] * b1v.x;
        acc[i][5] += av[i] * b1v.y;
        acc[i][6] += av[i] * b1v.z;
        acc[i][7] += av[i] * b1v.w;
      }
    }
    __syncthreads();
  }

  #pragma unroll
  for (int i = 0; i < 4; i++) {
    int n = n0 + row0 + i;
    if (n < N) {
      float4 o0, o1;
      o0.x = fmaxf(acc[i][0] + b1[c + 0], 0.f);
      o0.y = fmaxf(acc[i][1] + b1[c + 1], 0.f);
      o0.z = fmaxf(acc[i][2] + b1[c + 2], 0.f);
      o0.w = fmaxf(acc[i][3] + b1[c + 3], 0.f);
      o1.x = fmaxf(acc[i][4] + b1[c + 64], 0.f);
      o1.y = fmaxf(acc[i][5] + b1[c + 65], 0.f);
      o1.z = fmaxf(acc[i][6] + b1[c + 66], 0.f);
      o1.w = fmaxf(acc[i][7] + b1[c + 67], 0.f);
      *(float4*)(h + (size_t)n * DH + c) = o0;
      *(float4*)(h + (size_t)n * DH + c + 64) = o1;
    }
  }
  #undef LOADA
  #undef LOADB
}

// ---------- layer 2 per-segment: agg2[seg,:] = mean_h(seg) @ W_rel2[r] ----------
__global__ __launch_bounds__(256) void k_l2seg(const int* __restrict__ offs, const int* __restrict__ hist,
                                               const int* __restrict__ sorted_src, const float* __restrict__ h,
                                               const float* __restrict__ W2, float* __restrict__ agg2, int S) {
  int tid = threadIdx.x;
  int seg = blockIdx.x * 4 + (tid >> 6);
  int lane = tid & 63;
  if (seg >= S) return;
  int end = offs[seg];
  int cnt = hist[seg];
  int st = end - cnt;
  float2 a = make_float2(0.f, 0.f);
  for (int i = st; i < end; i++) {
    int s = sorted_src[i];
    float2 v = *(const float2*)(h + (size_t)s * DH + lane * 2);
    a.x += v.x;
    a.y += v.y;
  }
  int r = seg & (NR - 1);
  float4 w = *(const float4*)(W2 + (size_t)r * 256 + lane * 4);  // {W(d0,0),W(d0,1),W(d1,0),W(d1,1)}
  float t0 = a.x * w.x + a.y * w.z;
  float t1 = a.x * w.y + a.y * w.w;
  #pragma unroll
  for (int m = 32; m >= 1; m >>= 1) {
    t0 += __shfl_xor(t0, m);
    t1 += __shfl_xor(t1, m);
  }
  if (lane == 0) {
    float inv = 1.f / fmaxf((float)cnt, 1.f);
    agg2[(size_t)seg * 2 + 0] = t0 * inv;
    agg2[(size_t)seg * 2 + 1] = t1 * inv;
  }
}

// ---------- output: out[n] = sum_r agg2[n,r,:] + h[n] @ W_root2 + b2 ----------
__global__ __launch_bounds__(256) void k_out(const float* __restrict__ h, const float* __restrict__ agg2,
                                             const float* __restrict__ Wr2, const float* __restrict__ b2,
                                             float* __restrict__ out, int N) {
  long long gid = (long long)blockIdx.x * 256 + threadIdx.x;
  int n = (int)(gid >> 5);
  int lane = (int)(gid & 31);
  if (n >= N) return;
  float4 v = ((const float4*)(h + (size_t)n * DH))[lane];
  const float4* wr = (const float4*)(Wr2 + lane * 8);
  float4 w0 = wr[0];
  float4 w1 = wr[1];
  float t0 = v.x * w0.x + v.y * w0.z + v.z * w1.x + v.w * w1.z;
  float t1 = v.x * w0.y + v.y * w0.w + v.z * w1.y + v.w * w1.w;
  #pragma unroll
  for (int m = 16; m >= 1; m >>= 1) {
    t0 += __shfl_xor(t0, m, 32);
    t1 += __shfl_xor(t1, m, 32);
  }
  if (lane == 0) {
    float o0 = t0 + b2[0];
    float o1 = t1 + b2[1];
    #pragma unroll
    for (int r = 0; r < NR; r++) {
      o0 += agg2[((size_t)n * NR + r) * 2 + 0];
      o1 += agg2[((size_t)n * NR + r) * 2 + 1];
    }
    out[(size_t)n * 2 + 0] = o0;
    out[(size_t)n * 2 + 1] = o1;
  }
}

extern "C" void kernel_launch(void* const* d_in, const int* in_sizes, int n_in,
                              void* d_out, int out_size, void* d_ws, size_t ws_size,
                              hipStream_t stream) {
  const float* x   = (const float*)d_in[0];
  const int*   ei  = (const int*)d_in[1];
  const int*   et  = (const int*)d_in[2];
  const float* W1  = (const float*)d_in[3];
  const float* Wr1 = (const float*)d_in[4];
  const float* b1  = (const float*)d_in[5];
  const float* W2  = (const float*)d_in[6];
  const float* Wr2 = (const float*)d_in[7];
  const float* b2  = (const float*)d_in[8];
  float* out = (float*)d_out;

  int E = in_sizes[1] / 2;
  int N = in_sizes[0] / DH;
  int S = N * NR;
  const int* src = ei;
  const int* dst = ei + E;

  // workspace layout (ints first, 16B-aligned blocks)
  int* hist       = (int*)d_ws;                  // S
  int* offs       = hist + S;                    // S
  int* blksum     = offs + S;                    // 1024
  int* blkoff     = blksum + 1024;               // 1024
  int* sorted_src = blkoff + 1024;               // E
  size_t int_elems = (size_t)S * 2 + 2048 + E;
  int_elems = (int_elems + 3) & ~(size_t)3;      // 16B align
  float* agg1 = (float*)(hist + int_elems);      // S*128
  float* h    = agg1 + (size_t)S * DH;           // N*128
  float* agg2 = h + (size_t)N * DH;              // S*2

  hipMemsetAsync(hist, 0, sizeof(int) * (size_t)S, stream);

  k_hist<<<(E + 255) / 256, 256, 0, stream>>>(dst, et, hist, E);

  int NB = (S + 1023) / 1024;  // 391 for N=50000 (must be <= 512)
  k_scan_local<<<NB, 256, 0, stream>>>(hist, offs, blksum, S);
  k_scan_blk<<<1, 512, 0, stream>>>(blksum, blkoff, NB);
  k_scan_add<<<NB, 256, 0, stream>>>(offs, blkoff, S);

  k_scatter_idx<<<(E + 255) / 256, 256, 0, stream>>>(src, dst, et, offs, sorted_src, E);

  k_agg1<<<(S + 3) / 4, 256, 0, stream>>>(offs, hist, sorted_src, x, agg1, S);

  k_gemm1<<<(N + 63) / 64, 256, 0, stream>>>(agg1, x, W1, Wr1, b1, h, N);

  k_l2seg<<<(S + 3) / 4, 256, 0, stream>>>(offs, hist, sorted_src, h, W2, agg2, S);

  long long th2 = (long long)N * 32;
  k_out<<<(int)((th2 + 255) / 256), 256, 0, stream>>>(h, agg2, Wr2, b2, out, N);
}